// Round 7
// baseline (576.566 us; speedup 1.0000x reference)
//
#include <hip/hip_runtime.h>

// x: (64, 256, 56, 56) f32. Per (b,c): mag = sum(x^2). Per batch: keep channel
// iff mag > (128th largest mag in batch)  [reference: mask = mag > sorted[127]].
//
// Fused single-read: 1024 blocks (4/CU; LDS 26KB/block caps at 6/CU, VGPR<=128),
// 8 rounds x 2 planes/block staged in LDS across a per-batch arrival barrier.
// 128-block groups (bid>>7) are independent: group g handles batch r*8+g in
// round r. The LAST arriver (leader) computes the batch threshold and
// publishes it; others spin on cnt==129 then read one float. All cross-block
// words via relaxed AGENT-scope atomics (coherence-point ops, no L2 inv);
// store->add ordering via per-wave s_waitcnt vmcnt(0) (syncthreads drains
// other waves' stores). y stores nontemporal.

#define B 64
#define C 256
#define PLANE 3136       // 56*56
#define PLANE4 784       // 3136/4
#define KCH 128          // NUM_CHANNELS
#define NBLK 1024
#define PPR 2048         // planes per round
#define ROUNDS 8
#define BPB 128          // blocks per batch

typedef float f32x4 __attribute__((ext_vector_type(4)));

__device__ __forceinline__ float sumsq(f32x4 v) {
    float s = v.x * v.x;
    s = fmaf(v.y, v.y, s);
    s = fmaf(v.z, v.z, s);
    s = fmaf(v.w, v.w, s);
    return s;
}

__device__ __forceinline__ float aload(const float* p) {
    return __hip_atomic_load(p, __ATOMIC_RELAXED, __HIP_MEMORY_SCOPE_AGENT);
}
__device__ __forceinline__ void astore(float* p, float v) {
    __hip_atomic_store(p, v, __ATOMIC_RELAXED, __HIP_MEMORY_SCOPE_AGENT);
}

__global__ __launch_bounds__(256, 4) void fused2_kernel(
        const float* __restrict__ x, float* __restrict__ y,
        float* mag, int* cnt, float* thr) {
    const int tid  = threadIdx.x;
    const int lane = tid & 63;
    const int wid  = tid >> 6;

    __shared__ f32x4 pl[2][PLANE4];   // 25088 B: this round's two planes
    __shared__ float ws[2][4];
    __shared__ float lm[C];
    __shared__ int   lleader;
    __shared__ float lthr;

    for (int r = 0; r < ROUNDS; ++r) {
        const int p0   = r * PPR + 2 * blockIdx.x;
        const int bat  = p0 >> 8;
        const int base = bat << 8;

        const f32x4* __restrict__ xp0 =
            reinterpret_cast<const f32x4*>(x + (size_t)p0 * PLANE);
        const f32x4* __restrict__ xp1 = xp0 + PLANE4;

        // ---- phase A: stream planes into LDS, accumulate sum of squares ----
        float s0 = 0.f, s1 = 0.f;
        for (int i = tid; i < PLANE4; i += 256) {
            f32x4 v0 = xp0[i];
            f32x4 v1 = xp1[i];
            pl[0][i] = v0;
            pl[1][i] = v1;
            s0 += sumsq(v0);
            s1 += sumsq(v1);
        }
        for (int off = 32; off > 0; off >>= 1) {
            s0 += __shfl_down(s0, off, 64);
            s1 += __shfl_down(s1, off, 64);
        }
        if (lane == 0) { ws[0][wid] = s0; ws[1][wid] = s1; }
        __syncthreads();

        // every thread computes the block's two mags (bit-identical)
        const float m0 = (ws[0][0] + ws[0][1]) + (ws[0][2] + ws[0][3]);
        const float m1 = (ws[1][0] + ws[1][1]) + (ws[1][2] + ws[1][3]);

        // ---- publish mags, arrive; last arriver becomes leader ----
        if (tid == 0) {
            astore(&mag[p0], m0);
            astore(&mag[p0 + 1], m1);
            asm volatile("s_waitcnt vmcnt(0)" ::: "memory");  // mags durable
            int old = __hip_atomic_fetch_add(&cnt[bat], 1, __ATOMIC_RELAXED,
                                             __HIP_MEMORY_SCOPE_AGENT);
            lleader = (old == BPB - 1);
        }
        __syncthreads();

        if (lleader) {
            // all 128 blocks' mags are durable (each ordered store->add).
            const float mv = aload(&mag[base + tid]);
            lm[tid] = mv;
            __syncthreads();
            int gt = 0, eq = 0;
            for (int i = 0; i < C; ++i) {
                const float u = lm[i];
                gt += (u > mv);
                eq += (u == mv);
            }
            if (gt <= (KCH - 1) && (KCH - 1) < gt + eq) {
                astore(&thr[bat], mv);   // unique value; ties store same bits
                lthr = mv;
            }
            __syncthreads();             // drains every wave's thr store (vmcnt)
            if (tid == 0) {
                asm volatile("s_waitcnt vmcnt(0)" ::: "memory");
                __hip_atomic_fetch_add(&cnt[bat], 1, __ATOMIC_RELAXED,
                                       __HIP_MEMORY_SCOPE_AGENT);  // -> 129
            }
        } else {
            if (tid == 0) {
                while (__hip_atomic_load(&cnt[bat], __ATOMIC_RELAXED,
                                         __HIP_MEMORY_SCOPE_AGENT) < BPB + 1) {
                    __builtin_amdgcn_s_sleep(1);
                }
                asm volatile("" ::: "memory");   // no reorder of thr load above
                lthr = aload(&thr[bat]);
            }
        }
        __syncthreads();
        const float T = lthr;
        const bool keep0 = m0 > T;
        const bool keep1 = m1 > T;

        // ---- phase B: LDS -> y (nontemporal), zeros for dropped ----
        f32x4* __restrict__ yp0 = reinterpret_cast<f32x4*>(y + (size_t)p0 * PLANE);
        f32x4* __restrict__ yp1 = yp0 + PLANE4;
        const f32x4 z = {0.f, 0.f, 0.f, 0.f};
        if (keep0) {
            for (int i = tid; i < PLANE4; i += 256)
                __builtin_nontemporal_store(pl[0][i], yp0 + i);
        } else {
            for (int i = tid; i < PLANE4; i += 256)
                __builtin_nontemporal_store(z, yp0 + i);
        }
        if (keep1) {
            for (int i = tid; i < PLANE4; i += 256)
                __builtin_nontemporal_store(pl[1][i], yp1 + i);
        } else {
            for (int i = tid; i < PLANE4; i += 256)
                __builtin_nontemporal_store(z, yp1 + i);
        }
        __syncthreads();   // pl/lm/ws/lthr reused next round
    }
}

extern "C" void kernel_launch(void* const* d_in, const int* in_sizes, int n_in,
                              void* d_out, int out_size, void* d_ws, size_t ws_size,
                              hipStream_t stream) {
    const float* x = (const float*)d_in[0];
    float* y = (float*)d_out;
    float* mag = (float*)d_ws;            // 16384 floats
    int*   cnt = (int*)(mag + B * C);     // 64 ints
    float* thr = (float*)(cnt + B);       // 64 floats

    hipMemsetAsync(cnt, 0, B * sizeof(int), stream);
    fused2_kernel<<<NBLK, 256, 0, stream>>>(x, y, mag, cnt, thr);
}

// Round 8
// 75.382 us; speedup vs baseline: 7.6486x; 7.6486x over previous
//
#include <hip/hip_runtime.h>

// x: (64, 256, 56, 56) f32. Per (b,c): mag = sum(x^2). Per batch: keep channel
// iff count(mags in batch >= own mag) <= 127  (== mag > 128th-largest, tie-exact).
// y writes use nontemporal stores: y is never re-read, keep x L3-resident.
//
// Two-pass streaming structure. Measured 75.2 us = 512 MB fabric bytes at
// ~7 TB/s (box's measured fill-rate ceiling) — within ~3% of roofline.
// Fused single-read variants (R5-R7) were sync-bound at 570-970 us: per-batch
// agent-scope spin barriers cost ~65 us/round, dwarfing the 15 us byte saving.

#define B 64
#define C 256
#define PLANE 3136       // 56*56
#define PLANE4 784       // 3136/4
#define KCH 128          // NUM_CHANNELS

typedef float f32x4 __attribute__((ext_vector_type(4)));  // builtin-compatible

// ---------------- Kernel 1: per-plane sum of squares ----------------
__global__ __launch_bounds__(256) void mag_kernel(const float* __restrict__ x,
                                                  float* __restrict__ mag) {
    const int plane = blockIdx.x;  // b*C + c
    const f32x4* __restrict__ xp =
        reinterpret_cast<const f32x4*>(x + (size_t)plane * PLANE);
    float s = 0.f;
    for (int i = threadIdx.x; i < PLANE4; i += 256) {
        f32x4 v = xp[i];
        s = fmaf(v.x, v.x, s);
        s = fmaf(v.y, v.y, s);
        s = fmaf(v.z, v.z, s);
        s = fmaf(v.w, v.w, s);
    }
    // wave64 reduce
    for (int off = 32; off > 0; off >>= 1) s += __shfl_down(s, off, 64);
    __shared__ float ws4[4];
    const int lane = threadIdx.x & 63;
    const int wid  = threadIdx.x >> 6;
    if (lane == 0) ws4[wid] = s;
    __syncthreads();
    if (threadIdx.x == 0) {
        mag[plane] = (ws4[0] + ws4[1]) + (ws4[2] + ws4[3]);
    }
}

// ---------------- Kernel 2: rank test + masked copy / zero ----------------
__global__ __launch_bounds__(256) void write_kernel(const float* __restrict__ x,
                                                    const float* __restrict__ mag,
                                                    float* __restrict__ y) {
    const int plane = blockIdx.x;
    const int base  = plane & ~(C - 1);   // start of this batch's 256 mags

    // keep iff count(mags >= own) <= KCH-1
    __shared__ int cnts[4];
    const float m_own = mag[plane];
    const float mt    = mag[base + threadIdx.x];
    const unsigned long long ball = __ballot(mt >= m_own);
    const int lane = threadIdx.x & 63;
    const int wid  = threadIdx.x >> 6;
    if (lane == 0) cnts[wid] = __popcll(ball);
    __syncthreads();
    const bool keep = (cnts[0] + cnts[1] + cnts[2] + cnts[3]) <= (KCH - 1);

    const f32x4* __restrict__ xp =
        reinterpret_cast<const f32x4*>(x + (size_t)plane * PLANE);
    f32x4* __restrict__ yp = reinterpret_cast<f32x4*>(y + (size_t)plane * PLANE);
    if (keep) {
        for (int i = threadIdx.x; i < PLANE4; i += 256) {
            __builtin_nontemporal_store(xp[i], yp + i);
        }
    } else {
        const f32x4 z = {0.f, 0.f, 0.f, 0.f};
        for (int i = threadIdx.x; i < PLANE4; i += 256) {
            __builtin_nontemporal_store(z, yp + i);
        }
    }
}

extern "C" void kernel_launch(void* const* d_in, const int* in_sizes, int n_in,
                              void* d_out, int out_size, void* d_ws, size_t ws_size,
                              hipStream_t stream) {
    const float* x = (const float*)d_in[0];
    float* y = (float*)d_out;
    float* mag = (float*)d_ws;        // B*C floats = 64 KB

    mag_kernel<<<B * C, 256, 0, stream>>>(x, mag);
    write_kernel<<<B * C, 256, 0, stream>>>(x, mag, y);
}